// Round 10
// baseline (281.531 us; speedup 1.0000x reference)
//
#include <hip/hip_runtime.h>
#include <hip/hip_bf16.h>
#include <type_traits>

#define T_STEPS 256
#define BATCH   2048
#define INSZ    65
#define HID     64
#define ROWS    8        // batch rows per block -> 256 blocks = 1 block/CU
#define OUTSZ   7
#define NTHREADS 256

// LDS (shorts):
//  XB  [0,1024): x A-tile, M=16 (m = 2*row + tstep_local), K=64 frag-major:
//                element(m,k) at (k>>3)*128 + m*8 + (k&7)
//  HS0/HS1 [1024,2048): h buffers, COMPACT [8 rows][64 k] frag-major:
//                element(r,k) at (k>>3)*64 + r*8 + (k&7)
//                (h A-tile is 2x-replicated: A row m -> data row m>>1; the
//                 frag read uses (col>>1) addressing -> broadcast pairs, free)
#define XB   0
#define HS0  1024
#define HS1  1536

typedef __attribute__((ext_vector_type(8))) short bf16x8;  // 8 bf16 = 4 VGPRs
typedef __attribute__((ext_vector_type(4))) short short4v; // 4 bf16 = 2 VGPRs
typedef __attribute__((ext_vector_type(4))) float f32x4;

// f32->bf16 RNE via HIP intrinsic (round-2 post-mortem: no inline-asm cvt).
__device__ __forceinline__ short f2bf(float f) {
    __hip_bfloat16 b = __float2bfloat16(f);
    return (short)__builtin_bit_cast(unsigned short, b);
}
__device__ __forceinline__ float bf2f(short s) {
    union { unsigned u; float f; } v;
    v.u = ((unsigned)(unsigned short)s) << 16;
    return v.f;
}

// Gate pre-activations PRE-SCALED (folded into weights/bias):
//   i,f,o scaled by -log2(e)  -> sigmoid(x) = rcp(1 + exp2(x'))
//   g     scaled by +2log2(e); cell state carried pre-scaled c' = 2log2(e)*c
#define NLOG2E -1.4426950408889634f
#define SGSCL   2.8853900817779268f

__device__ __forceinline__ float sigm2(float a) {
    return __builtin_amdgcn_rcpf(1.0f + __builtin_amdgcn_exp2f(a));
}

// LDS-visibility-only barrier (round-4 win: no vmcnt drain; prefetch global
// loads stay in flight across barriers).
#define BAR() do { \
    asm volatile("s_waitcnt lgkmcnt(0)" ::: "memory"); \
    __builtin_amdgcn_s_barrier(); \
} while (0)

#define IC(n) std::integral_constant<int, n>{}

// (,1): no VGPR cap (512); grid=256 -> 1 block/CU regardless. (,4) disaster
// (round 1: spill), (,2) proven but here residency is grid-limited anyway.
__global__ __launch_bounds__(NTHREADS, 1)
void lstm_fused(const float* __restrict__ x,    const float* __restrict__ W_ih,
                const float* __restrict__ W_hh, const float* __restrict__ b_ih,
                const float* __restrict__ b_hh, const float* __restrict__ fc_W,
                const float* __restrict__ fc_b, float* __restrict__ out)
{
    __shared__ __align__(16) short Abuf[2048];

    const int tid  = threadIdx.x;
    const int w    = tid >> 6;        // wave 0..3 = hidden-col tile [16w,16w+16)
    const int lane = tid & 63;
    const int quad = lane >> 4;       // lane activates rows 2*quad, 2*quad+1
    const int col  = lane & 15;
    const int b0   = blockIdx.x * ROWS;

    // zero both h buffers (1024 shorts)
    Abuf[HS0 + tid]       = 0;
    Abuf[HS0 + 256 + tid] = 0;
    Abuf[HS0 + 512 + tid] = 0;
    Abuf[HS0 + 768 + tid] = 0;

    // ---- weight fragments (B layout: n = lane&15, k = quad*8+j), pre-scaled ----
    // kc 0,1: x-part (k 0..63 of W_ih); kc 2,3: h-part (W_hh). k=64 -> acc_bx fold.
    bf16x8 wfrag[4][4];
    float  wl[4];
    f32x4  bias4[4];
    #pragma unroll
    for (int gt = 0; gt < 4; ++gt) {
        const float sc = (gt == 2) ? SGSCL : NLOG2E;
        const int n = gt * 64 + w * 16 + col;
        #pragma unroll
        for (int kc = 0; kc < 2; ++kc) {
            bf16x8 f;
            #pragma unroll
            for (int j = 0; j < 8; ++j)
                f[j] = f2bf(W_ih[n * INSZ + kc * 32 + quad * 8 + j] * sc);
            wfrag[gt][kc] = f;
        }
        #pragma unroll
        for (int kc = 2; kc < 4; ++kc) {
            bf16x8 f;
            #pragma unroll
            for (int j = 0; j < 8; ++j)
                f[j] = f2bf(W_hh[n * HID + (kc - 2) * 32 + quad * 8 + j] * sc);
            wfrag[gt][kc] = f;
        }
        wl[gt] = W_ih[n * INSZ + 64] * sc;
        const float bv = (b_ih[n] + b_hh[n]) * sc;
        bias4[gt] = (f32x4){bv, bv, bv, bv};
    }

    // x A-frag read (A row m=col, k=quad*8+j): lo chunk + hi chunk (+512)
    const int rbx = quad * 128 + col * 8;
    // h A-frag read from COMPACT buffer: data row = col>>1 (2x replication)
    const int rbh = quad * 64 + (col >> 1) * 8;      // hi chunk +256
    // h write: k = 16w+col, rows 2*quad (+8*j for 2*quad+j)
    const int hwb = (2 * w + (col >> 3)) * 64 + 16 * quad + (col & 7);
    // x stage write: m = col, kq = w*4+quad, 4 shorts
    const int kq = w * 4 + quad;
    const int xswoff = (kq >> 1) * 128 + col * 8 + (kq & 1) * 4;

    // staging global ptr: row = col>>1, tl = col&1 folded in
    const float* xgp = x + (size_t)(b0 + (col >> 1)) * T_STEPS * INSZ
                         + (col & 1) * INSZ + kq * 4;
    // fixup ptrs (k=64) for rows 2q, 2q+1
    const float* xeA = x + (size_t)(b0 + 2 * quad) * T_STEPS * INSZ + 64;
    const float* xeB = xeA + (size_t)T_STEPS * INSZ;

    // ---- prologue: stage group 0 (t2=0), preload ldA (group 1, t2=2) ----
    {
        short4v pk0;
        #pragma unroll
        for (int j = 0; j < 4; ++j) pk0[j] = f2bf(xgp[j]);
        *(short4v*)&Abuf[XB + xswoff] = pk0;
    }
    float ldA[4];
    #pragma unroll
    for (int j = 0; j < 4; ++j) ldA[j] = xgp[2 * INSZ + j];
    float fx[4] = { xeA[0], xeA[INSZ], xeB[0], xeB[INSZ] };  // reg i: row 2q+(i>>1), tl i&1
    float cc[2] = { 0.0f, 0.0f };   // pre-scaled c' for rows 2q, 2q+1
    f32x4 acc_bx[4];
    __syncthreads();

    // batched x-MFMA for group 0: acc_bx[gt] reg i = bias + xg[row 2q+(i>>1)][tl=i&1]
    {
        const bf16x8 xb0 = *(const bf16x8*)&Abuf[XB + rbx];
        const bf16x8 xb1 = *(const bf16x8*)&Abuf[XB + rbx + 512];
        #pragma unroll
        for (int gt = 0; gt < 4; ++gt) {
            f32x4 a = __builtin_amdgcn_mfma_f32_16x16x32_bf16(xb0, wfrag[gt][0], bias4[gt], 0, 0, 0);
            a = __builtin_amdgcn_mfma_f32_16x16x32_bf16(xb1, wfrag[gt][1], a, 0, 0, 0);
            #pragma unroll
            for (int i = 0; i < 4; ++i)
                a[i] = __builtin_fmaf(wl[gt], fx[i], a[i]);
            acc_bx[gt] = a;
        }
    }
    // Guard: s0's shadow overwrites XB; other waves may still be in their
    // prologue x-MFMA reads of XB. One full barrier separates them.
    __syncthreads();

    // One LSTM step (S = 0/1 within the 2-step group).
    // Critical path: ds_read h (compact, broadcast) -> 8 MFMA -> 2-row
    // activation -> 2 h writes. shadow(): off-path work before the barrier.
    auto lstm_step = [&](auto Sc, int HR, int HW, auto&& shadow) {
        constexpr int S = decltype(Sc)::value;
        const bf16x8 a2 = *(const bf16x8*)&Abuf[HR + rbh];        // h k 0..31
        const bf16x8 a3 = *(const bf16x8*)&Abuf[HR + rbh + 256];  // h k 32..63
        f32x4 g0 = __builtin_amdgcn_mfma_f32_16x16x32_bf16(a2, wfrag[0][2], acc_bx[0], 0, 0, 0);
        g0 = __builtin_amdgcn_mfma_f32_16x16x32_bf16(a3, wfrag[0][3], g0, 0, 0, 0);
        f32x4 g1 = __builtin_amdgcn_mfma_f32_16x16x32_bf16(a2, wfrag[1][2], acc_bx[1], 0, 0, 0);
        g1 = __builtin_amdgcn_mfma_f32_16x16x32_bf16(a3, wfrag[1][3], g1, 0, 0, 0);
        f32x4 g2 = __builtin_amdgcn_mfma_f32_16x16x32_bf16(a2, wfrag[2][2], acc_bx[2], 0, 0, 0);
        g2 = __builtin_amdgcn_mfma_f32_16x16x32_bf16(a3, wfrag[2][3], g2, 0, 0, 0);
        f32x4 g3 = __builtin_amdgcn_mfma_f32_16x16x32_bf16(a2, wfrag[3][2], acc_bx[3], 0, 0, 0);
        g3 = __builtin_amdgcn_mfma_f32_16x16x32_bf16(a3, wfrag[3][3], g3, 0, 0, 0);
        #pragma unroll
        for (int j = 0; j < 2; ++j) {          // local row 2*quad + j
            const int i0 = 2 * j + S;          // compile-time reg index
            const float gi = sigm2(g0[i0]);
            const float gf = sigm2(g1[i0]);
            const float rg = __builtin_amdgcn_rcpf(1.0f + __builtin_amdgcn_exp2f(g2[i0]));
            const float gg = __builtin_fmaf(rg, -2.0f * SGSCL, SGSCL);
            const float go = sigm2(g3[i0]);
            cc[j] = __builtin_fmaf(gf, cc[j], gi * gg);
            const float rc = __builtin_amdgcn_rcpf(1.0f + __builtin_amdgcn_exp2f(cc[j]));
            const float h  = go * __builtin_fmaf(rc, -2.0f, 1.0f);
            Abuf[HW + hwb + 8 * j] = f2bf(h);
        }
        shadow();
        BAR();   // lgkmcnt-only: prefetch vmem stays in flight
    };

    for (int t2 = 0; t2 < T_STEPS; t2 += 2) {
        // group-top global loads (never drained at a barrier):
        //   ldB: x feats for group t2+4; nf: k=64 fixups for group t2+2
        // ROUND-8 BUG FIX: effective timestep = tsb + (col&1) must reach 255
        // for the last REAL prefetch (t2=250 -> group 254). Clamp at 254, not
        // 252 (252 silently redirected group 254's x to t=252/253 -> absmax 0.1).
        int tsb = t2 + 4; if (tsb > 254) tsb = 254;
        int tfc = t2 + 2; if (tfc > 254) tfc = 254;
        float ldB[4];
        #pragma unroll
        for (int j = 0; j < 4; ++j) ldB[j] = xgp[tsb * INSZ + j];
        float nf[4] = { xeA[tfc * INSZ], xeA[(tfc + 1) * INSZ],
                        xeB[tfc * INSZ], xeB[(tfc + 1) * INSZ] };
        // s0: read HS1 (h_{t2-1}), write HS0 (h_t2); shadow: cvt + stage XB
        // for group t2+2 (old XB consumed in previous s1 shadow).
        lstm_step(IC(0), HS1, HS0, [&] {
            short4v pk;
            #pragma unroll
            for (int j = 0; j < 4; ++j) pk[j] = f2bf(ldA[j]);
            *(short4v*)&Abuf[XB + xswoff] = pk;
        });
        // s1: read HS0 (h_t2), write HS1 (h_{t2+1}); shadow: batched x-MFMA for
        // group t2+2 (XB staged in s0, synced by s0's BAR; acc_bx consumed above).
        lstm_step(IC(1), HS0, HS1, [&] {
            const bf16x8 xb0 = *(const bf16x8*)&Abuf[XB + rbx];
            const bf16x8 xb1 = *(const bf16x8*)&Abuf[XB + rbx + 512];
            #pragma unroll
            for (int gt = 0; gt < 4; ++gt) {
                f32x4 a = __builtin_amdgcn_mfma_f32_16x16x32_bf16(xb0, wfrag[gt][0], bias4[gt], 0, 0, 0);
                a = __builtin_amdgcn_mfma_f32_16x16x32_bf16(xb1, wfrag[gt][1], a, 0, 0, 0);
                #pragma unroll
                for (int i = 0; i < 4; ++i)
                    a[i] = __builtin_fmaf(wl[gt], nf[i], a[i]);
                acc_bx[gt] = a;
            }
            #pragma unroll
            for (int j = 0; j < 4; ++j) ldA[j] = ldB[j];
        });
    }

    // ---- FC(64->7) + sigmoid; h_255 lives in HS1, compact [8][64] ----
    // last step ended with BAR(): all h writes visible.
    if (tid < ROWS * OUTSZ) {   // 56 threads
        const int m = tid & 7;
        const int o = tid >> 3;
        float s = fc_b[o];
        #pragma unroll
        for (int k = 0; k < HID; ++k)
            s += bf2f(Abuf[HS1 + (k >> 3) * 64 + m * 8 + (k & 7)]) * fc_W[o * HID + k];
        out[(size_t)(b0 + m) * OUTSZ + o] =
            __builtin_amdgcn_rcpf(1.0f + __builtin_amdgcn_exp2f(NLOG2E * s));
    }
}

extern "C" void kernel_launch(void* const* d_in, const int* in_sizes, int n_in,
                              void* d_out, int out_size, void* d_ws, size_t ws_size,
                              hipStream_t stream) {
    const float* x    = (const float*)d_in[0];
    const float* W_ih = (const float*)d_in[1];
    const float* W_hh = (const float*)d_in[2];
    const float* b_ih = (const float*)d_in[3];
    const float* b_hh = (const float*)d_in[4];
    const float* fc_W = (const float*)d_in[5];
    const float* fc_b = (const float*)d_in[6];
    float* out = (float*)d_out;

    dim3 grid(BATCH / ROWS);    // 256 blocks -> 1 per CU
    dim3 block(NTHREADS);       // 4 waves
    hipLaunchKernelGGL(lstm_fused, grid, block, 0, stream,
                       x, W_ih, W_hh, b_ih, b_hh, fc_W, fc_b, out);
}

// Round 11
// 246.987 us; speedup vs baseline: 1.1399x; 1.1399x over previous
//
#include <hip/hip_runtime.h>
#include <hip/hip_bf16.h>
#include <type_traits>

#define T_STEPS 256
#define BATCH   2048
#define INSZ    65
#define HID     64
#define ROWS    4        // batch rows per block -> 512 blocks = 2 blocks/CU
#define OUTSZ   7
#define NTHREADS 256

// LDS (shorts):
//  XB [0,1024): x A-tile for one 4-step group, M=16 (m = 4*row + tstep_local),
//               K=64 frag-major: element(m,k) at (k>>3)*128 + m*8 + (k&7)
//  HS0/HS1 [1024,1536): h slots (256 shorts each),
//               element(row,k) at (k>>3)*32 + row*8 + (k&7)
#define XB   0
#define HS0  1024
#define HS1  1280

typedef __attribute__((ext_vector_type(8))) short bf16x8;  // 8 bf16 = 4 VGPRs
typedef __attribute__((ext_vector_type(4))) short short4v; // 4 bf16 = 2 VGPRs
typedef __attribute__((ext_vector_type(4))) float f32x4;

// f32->bf16 RNE via HIP intrinsic (round-2 post-mortem: no inline-asm cvt).
__device__ __forceinline__ short f2bf(float f) {
    __hip_bfloat16 b = __float2bfloat16(f);
    return (short)__builtin_bit_cast(unsigned short, b);
}
__device__ __forceinline__ float bf2f(short s) {
    union { unsigned u; float f; } v;
    v.u = ((unsigned)(unsigned short)s) << 16;
    return v.f;
}

// Gate pre-activations PRE-SCALED (folded into weights/bias):
//   i,f,o scaled by -log2(e)  -> sigmoid(x) = rcp(1 + exp2(x'))
//   g     scaled by +2log2(e); cell state carried pre-scaled c' = 2log2(e)*c
#define NLOG2E -1.4426950408889634f
#define SGSCL   2.8853900817779268f

__device__ __forceinline__ float sigm2(float a) {
    return __builtin_amdgcn_rcpf(1.0f + __builtin_amdgcn_exp2f(a));
}

// LDS-visibility-only barrier (round-4 win: no vmcnt drain; prefetch global
// loads stay in flight across barriers).
#define BAR() do { \
    asm volatile("s_waitcnt lgkmcnt(0)" ::: "memory"); \
    __builtin_amdgcn_s_barrier(); \
} while (0)

#define IC(n) std::integral_constant<int, n>{}

// launch_bounds(,2): VGPR cap 256, no spill (rounds 3-7 proven).
// (,4) caps arch VGPRs at 64 -> 909MB scratch spill (round-1 disaster).
// Round-10 A/B: ROWS=8 @1 wave/SIMD = 140us (latency exposed); this 2-blocks/CU
// anti-phased config is the latency-hiding optimum for this decomposition.
__global__ __launch_bounds__(NTHREADS, 2)
void lstm_fused(const float* __restrict__ x,    const float* __restrict__ W_ih,
                const float* __restrict__ W_hh, const float* __restrict__ b_ih,
                const float* __restrict__ b_hh, const float* __restrict__ fc_W,
                const float* __restrict__ fc_b, float* __restrict__ out)
{
    __shared__ __align__(16) short Abuf[1536];

    const int tid  = threadIdx.x;
    const int w    = tid >> 6;        // wave 0..3 = hidden-col tile [16w,16w+16)
    const int lane = tid & 63;
    const int quad = lane >> 4;       // batch row this lane activates / tl for staging
    const int col  = lane & 15;
    const int b0   = blockIdx.x * ROWS;

    // zero h slots (x buffer fully staged before first read)
    Abuf[HS0 + tid] = 0;   // covers HS0 ...
    Abuf[HS1 + tid] = 0;   // ... and HS1

    // ---- weight fragments (B layout: n = lane&15, k = quad*8+j), pre-scaled ----
    // kc 0,1: x-part (k 0..63 of W_ih); kc 2,3: h-part (W_hh). k=64 -> acc_bx fold.
    bf16x8 wfrag[4][4];
    float  wl[4];
    f32x4  bias4[4];
    #pragma unroll
    for (int gt = 0; gt < 4; ++gt) {
        const float sc = (gt == 2) ? SGSCL : NLOG2E;
        const int n = gt * 64 + w * 16 + col;
        #pragma unroll
        for (int kc = 0; kc < 2; ++kc) {
            bf16x8 f;
            #pragma unroll
            for (int j = 0; j < 8; ++j)
                f[j] = f2bf(W_ih[n * INSZ + kc * 32 + quad * 8 + j] * sc);
            wfrag[gt][kc] = f;
        }
        #pragma unroll
        for (int kc = 2; kc < 4; ++kc) {
            bf16x8 f;
            #pragma unroll
            for (int j = 0; j < 8; ++j)
                f[j] = f2bf(W_hh[n * HID + (kc - 2) * 32 + quad * 8 + j] * sc);
            wfrag[gt][kc] = f;
        }
        wl[gt] = W_ih[n * INSZ + 64] * sc;
        const float bv = (b_ih[n] + b_hh[n]) * sc;
        bias4[gt] = (f32x4){bv, bv, bv, bv};
    }

    // h A-frag read: A row m holds h[row m>>2] (replication) -> gate at any reg.
    const int rbase = quad * 32 + (col >> 2) * 8;
    // batched-x A-frag read: A row m = col holds x[row m>>2][t + (m&3)][k]
    const int rbx   = quad * 128 + col * 8;
    const int hwoff = (2 * w + (col >> 3)) * 32 + quad * 8 + (col & 7);  // h write
    // x stage write: thread (w,lane) owns (row w, tl=quad, feats col*4..col*4+3)
    //   m = 4*w + quad; k = col*4 -> addr = (col>>1)*128 + col... (frag-major)
    const int xswoff = (col >> 1) * 128 + (4 * w + quad) * 8 + (col & 1) * 4;

    const float* xr  = x + (size_t)(b0 + w)    * T_STEPS * INSZ;       // staging row
    const float* xep = x + (size_t)(b0 + quad) * T_STEPS * INSZ + 64;  // k=64 fixup

    // ---- prologue: stage group 0 (ts = quad), preload ldA (ts = 4+quad) ----
    {
        short4v pk0;
        #pragma unroll
        for (int j = 0; j < 4; ++j)
            pk0[j] = f2bf(xr[quad * INSZ + col * 4 + j]);
        *(short4v*)&Abuf[XB + xswoff] = pk0;
    }
    float ldA[4];
    #pragma unroll
    for (int j = 0; j < 4; ++j) ldA[j] = xr[(4 + quad) * INSZ + col * 4 + j];
    float fx[4];
    #pragma unroll
    for (int s = 0; s < 4; ++s) fx[s] = xep[s * INSZ];
    float c = 0.0f;   // carried pre-scaled: c' = SGSCL * c_true
    f32x4 acc_bx[4];
    __syncthreads();

    // batched x-MFMA for group 0: acc_bx[gt] reg s = bias + xg[row quad][t=s][col]
    {
        const bf16x8 xb0 = *(const bf16x8*)&Abuf[XB + rbx];
        const bf16x8 xb1 = *(const bf16x8*)&Abuf[XB + rbx + 512];
        #pragma unroll
        for (int gt = 0; gt < 4; ++gt) {
            f32x4 a = __builtin_amdgcn_mfma_f32_16x16x32_bf16(xb0, wfrag[gt][0], bias4[gt], 0, 0, 0);
            a = __builtin_amdgcn_mfma_f32_16x16x32_bf16(xb1, wfrag[gt][1], a, 0, 0, 0);
            #pragma unroll
            for (int i = 0; i < 4; ++i)
                a[i] = __builtin_fmaf(wl[gt], fx[i], a[i]);
            acc_bx[gt] = a;
        }
    }
    // no barrier needed: XB next written in s1 (post-BAR(s0)); s0 reads zeroed HS1.

    // One LSTM step. Round-11 chain trims vs round 7:
    //  (1) h-MFMA pair SPLIT: two independent MFMAs (C=acc_bx / C=0) + scalar
    //      add -- removes one MFMA latency from the serial chain; all 8 MFMAs
    //      issue back-to-back with no inter-dependency.
    //  (2) h = fma(go2, rc, go) with go2 = -2*go precomputed in parallel with
    //      the rc chain -- one dependency level after rc instead of two.
    // Gate value for step S is gA[S]+gB[S] (x-MFMA put xg[row q][t+S] in reg S).
    auto lstm_step = [&](auto Sc, int HR, int HW, auto&& shadow) {
        constexpr int S = decltype(Sc)::value;
        const bf16x8 a2 = *(const bf16x8*)&Abuf[HR + rbase];        // h lo
        const bf16x8 a3 = *(const bf16x8*)&Abuf[HR + rbase + 128];  // h hi
        const f32x4 z4 = {0.0f, 0.0f, 0.0f, 0.0f};
        f32x4 gA0 = __builtin_amdgcn_mfma_f32_16x16x32_bf16(a2, wfrag[0][2], acc_bx[0], 0, 0, 0);
        f32x4 gB0 = __builtin_amdgcn_mfma_f32_16x16x32_bf16(a3, wfrag[0][3], z4,        0, 0, 0);
        f32x4 gA1 = __builtin_amdgcn_mfma_f32_16x16x32_bf16(a2, wfrag[1][2], acc_bx[1], 0, 0, 0);
        f32x4 gB1 = __builtin_amdgcn_mfma_f32_16x16x32_bf16(a3, wfrag[1][3], z4,        0, 0, 0);
        f32x4 gA2 = __builtin_amdgcn_mfma_f32_16x16x32_bf16(a2, wfrag[2][2], acc_bx[2], 0, 0, 0);
        f32x4 gB2 = __builtin_amdgcn_mfma_f32_16x16x32_bf16(a3, wfrag[2][3], z4,        0, 0, 0);
        f32x4 gA3 = __builtin_amdgcn_mfma_f32_16x16x32_bf16(a2, wfrag[3][2], acc_bx[3], 0, 0, 0);
        f32x4 gB3 = __builtin_amdgcn_mfma_f32_16x16x32_bf16(a3, wfrag[3][3], z4,        0, 0, 0);
        const float v0 = gA0[S] + gB0[S];
        const float v1 = gA1[S] + gB1[S];
        const float v2 = gA2[S] + gB2[S];
        const float v3 = gA3[S] + gB3[S];
        const float gi = sigm2(v0);
        const float gf = sigm2(v1);
        // g-gate pre-scaled by SGSCL: gg = SGSCL*tanh(g) = SGSCL - 2*SGSCL*r
        const float rg = __builtin_amdgcn_rcpf(1.0f + __builtin_amdgcn_exp2f(v2));
        const float gg = __builtin_fmaf(rg, -2.0f * SGSCL, SGSCL);
        const float go = sigm2(v3);
        const float go2 = -2.0f * go;                // off the rc chain
        c = __builtin_fmaf(gf, c, gi * gg);          // c' = SGSCL*c_true
        const float rc = __builtin_amdgcn_rcpf(1.0f + __builtin_amdgcn_exp2f(c));
        const float h  = __builtin_fmaf(go2, rc, go);   // go*(1-2rc)
        Abuf[HW + hwoff] = f2bf(h);                  // h_t
        shadow();
        BAR();   // lgkmcnt-only: prefetch vmem stays in flight
    };

    for (int t = 0; t < T_STEPS; t += 4) {
        // group-top global loads (never drained at a barrier):
        //   ldB: x feats for group t+8 (consumed next group)
        //   nf : k=64 fixup values for group t+4 (consumed in s3 shadow)
        int tsb = t + 8 + quad; tsb = tsb > 255 ? 255 : tsb;
        float ldB[4], nf[4];
        #pragma unroll
        for (int j = 0; j < 4; ++j) ldB[j] = xr[tsb * INSZ + col * 4 + j];
        #pragma unroll
        for (int s = 0; s < 4; ++s) {
            int tf = t + 4 + s; tf = tf > 255 ? 255 : tf;
            nf[s] = xep[tf * INSZ];
        }
        short4v pk;
        // s0: convert ldA (group t+4 feats) to bf16 in the activation shadow
        lstm_step(IC(0), HS1, HS0, [&] {
            #pragma unroll
            for (int j = 0; j < 4; ++j) pk[j] = f2bf(ldA[j]);
        });
        // s1: stage write (post-BAR(s0): prior XB readers done; its own reader
        // is s3, one barrier later)
        lstm_step(IC(1), HS0, HS1, [&] {
            *(short4v*)&Abuf[XB + xswoff] = pk;
        });
        lstm_step(IC(2), HS1, HS0, [&] {});
        // s3: batched x-MFMA for group t+4 (8 MFMA + fixup fma, off-path);
        // old acc_bx consumed by this step's h-MFMA above, safe to overwrite.
        lstm_step(IC(3), HS0, HS1, [&] {
            const bf16x8 xb0 = *(const bf16x8*)&Abuf[XB + rbx];
            const bf16x8 xb1 = *(const bf16x8*)&Abuf[XB + rbx + 512];
            #pragma unroll
            for (int gt = 0; gt < 4; ++gt) {
                f32x4 a = __builtin_amdgcn_mfma_f32_16x16x32_bf16(xb0, wfrag[gt][0], bias4[gt], 0, 0, 0);
                a = __builtin_amdgcn_mfma_f32_16x16x32_bf16(xb1, wfrag[gt][1], a, 0, 0, 0);
                #pragma unroll
                for (int i = 0; i < 4; ++i)
                    a[i] = __builtin_fmaf(wl[gt], nf[i], a[i]);
                acc_bx[gt] = a;
            }
            #pragma unroll
            for (int j = 0; j < 4; ++j) ldA[j] = ldB[j];
        });
    }

    // ---- FC(64->7) + sigmoid; h_255 lives in HS1 (frag-major) ----
    // last step ended with BAR(): all h writes visible.
    if (tid < ROWS * OUTSZ) {
        const int m = tid & 3;
        const int o = tid >> 2;
        float s = fc_b[o];
        #pragma unroll
        for (int k = 0; k < HID; ++k)
            s += bf2f(Abuf[HS1 + (k >> 3) * 32 + m * 8 + (k & 7)]) * fc_W[o * HID + k];
        out[(size_t)(b0 + m) * OUTSZ + o] =
            __builtin_amdgcn_rcpf(1.0f + __builtin_amdgcn_exp2f(NLOG2E * s));
    }
}

extern "C" void kernel_launch(void* const* d_in, const int* in_sizes, int n_in,
                              void* d_out, int out_size, void* d_ws, size_t ws_size,
                              hipStream_t stream) {
    const float* x    = (const float*)d_in[0];
    const float* W_ih = (const float*)d_in[1];
    const float* W_hh = (const float*)d_in[2];
    const float* b_ih = (const float*)d_in[3];
    const float* b_hh = (const float*)d_in[4];
    const float* fc_W = (const float*)d_in[5];
    const float* fc_b = (const float*)d_in[6];
    float* out = (float*)d_out;

    dim3 grid(BATCH / ROWS);    // 512 blocks -> 2 per CU
    dim3 block(NTHREADS);       // 4 waves
    hipLaunchKernelGGL(lstm_fused, grid, block, 0, stream,
                       x, W_ih, W_hh, b_ih, b_hh, fc_W, fc_b, out);
}